// Round 4
// baseline (1034.320 us; speedup 1.0000x reference)
//
#include <hip/hip_runtime.h>
#include <hip/hip_bf16.h>
#include <math.h>

#define Nn 50000
#define Ee 1600000
#define RR 3
#define RN (RR * Nn)
#define FIN 770
#define KPAD1 800

typedef __attribute__((ext_vector_type(8))) short short8;
typedef __attribute__((ext_vector_type(4))) float floatx4;

static __device__ __forceinline__ unsigned short f2bf(float v) {
  __hip_bfloat16 h = __float2bfloat16(v);
  return *(unsigned short*)&h;
}

// ---------------------------------------------------------------------------
// CSR build: counts -> exclusive scan -> fill (edge list identical all layers)
// ---------------------------------------------------------------------------
__global__ __launch_bounds__(256) void count_kernel(const int* __restrict__ ei,
                                                    const int* __restrict__ et,
                                                    int* __restrict__ counts) {
  int e = blockIdx.x * 256 + threadIdx.x;
  if (e >= Ee) return;
  int col = ei[Ee + e];
  int r = et[e];
  atomicAdd(&counts[r * Nn + col], 1);
}

__global__ __launch_bounds__(256) void scan1_kernel(const int* __restrict__ counts,
                                                    int* __restrict__ offs,
                                                    int* __restrict__ bsums, int n) {
  __shared__ int sh[256];
  int t = threadIdx.x;
  int base = blockIdx.x * 1024 + t * 4;
  int v0 = (base + 0 < n) ? counts[base + 0] : 0;
  int v1 = (base + 1 < n) ? counts[base + 1] : 0;
  int v2 = (base + 2 < n) ? counts[base + 2] : 0;
  int v3 = (base + 3 < n) ? counts[base + 3] : 0;
  int tot = v0 + v1 + v2 + v3;
  sh[t] = tot;
  __syncthreads();
  for (int off = 1; off < 256; off <<= 1) {
    int v = (t >= off) ? sh[t - off] : 0;
    __syncthreads();
    sh[t] += v;
    __syncthreads();
  }
  int run = sh[t] - tot;
  if (base + 0 < n) offs[base + 0] = run; run += v0;
  if (base + 1 < n) offs[base + 1] = run; run += v1;
  if (base + 2 < n) offs[base + 2] = run; run += v2;
  if (base + 3 < n) offs[base + 3] = run;
  if (t == 255) bsums[blockIdx.x] = sh[255];
}

__global__ __launch_bounds__(256) void scan_top_kernel(int* __restrict__ bsums, int nb) {
  __shared__ int sh[256];
  int t = threadIdx.x;
  int v = (t < nb) ? bsums[t] : 0;
  sh[t] = v;
  __syncthreads();
  for (int off = 1; off < 256; off <<= 1) {
    int x = (t >= off) ? sh[t - off] : 0;
    __syncthreads();
    sh[t] += x;
    __syncthreads();
  }
  if (t < nb) bsums[t] = sh[t] - v;
}

__global__ __launch_bounds__(256) void scan_add_kernel(int* __restrict__ offs,
                                                       const int* __restrict__ bsums,
                                                       int n) {
  int i = blockIdx.x * 256 + threadIdx.x;
  if (i > n) return;
  if (i == n) { offs[n] = Ee; return; }
  offs[i] += bsums[i >> 10];
}

__global__ __launch_bounds__(256) void fill_kernel(const int* __restrict__ ei,
                                                   const int* __restrict__ et,
                                                   const int* __restrict__ offs,
                                                   int* __restrict__ cursor,
                                                   int* __restrict__ srcs) {
  int e = blockIdx.x * 256 + threadIdx.x;
  if (e >= Ee) return;
  int row = ei[e];
  int col = ei[Ee + e];
  int r = et[e];
  int s = r * Nn + col;
  int pos = offs[s] + atomicAdd(&cursor[s], 1);
  srcs[pos] = row;
}

// ---------------------------------------------------------------------------
// Weight prep: Wt (bf16, n-major) [256][Kpad]; cols 0..191 = W[r], 192..255 = root
// ---------------------------------------------------------------------------
__global__ __launch_bounds__(256) void prep_wt_kernel(const float* __restrict__ W,
                                                      const float* __restrict__ root,
                                                      unsigned short* __restrict__ Wt,
                                                      int K, int Kpad) {
  int i = blockIdx.x * 256 + threadIdx.x;
  if (i >= 256 * Kpad) return;
  int c = i / Kpad, k = i % Kpad;
  float v = 0.f;
  if (k < K) {
    if (c < 192) {
      int r = c >> 6, h = c & 63;
      v = W[((long)r * K + k) * 64 + h];
    } else {
      v = root[k * 64 + (c - 192)];
    }
  }
  Wt[i] = f2bf(v);
}

// head weights: Wt_h [256][64] bf16 (rows 128..255 zero), biasH[128] fp32
__global__ __launch_bounds__(256) void prep_wth_kernel(const float* __restrict__ ew1,
                                                       const float* __restrict__ eb1,
                                                       unsigned short* __restrict__ Wth,
                                                       float* __restrict__ biasH) {
  int i = blockIdx.x * 256 + threadIdx.x;
  if (i < 128) biasH[i] = (i < 64) ? eb1[i] : 0.f;
  if (i >= 256 * 64) return;
  int c = i >> 6, k = i & 63;
  float v = 0.f;
  if (c < 64) v = ew1[k * 64 + c];
  else if (c < 128) v = ew1[(64 + k) * 64 + (c - 64)];
  Wth[i] = f2bf(v);
}

// ---------------------------------------------------------------------------
// bf16 MFMA GEMM, SOFTWARE-PIPELINED: C[M][Ncol](bf16) = A[M][K](fp32) @ Wt^T
// tile 64x256, BK=32, 4 waves; each wave 64x64 via 4x4 of 16x16x32 MFMA.
// Iteration k's global loads (A 32B/thread, B 64B/thread) issue between the
// ds_reads and the MFMAs of iteration k-1; their vmcnt-wait lands at the next
// LDS store — hides the ~900cyc HBM latency behind 16 MFMAs + barrier.
// ---------------------------------------------------------------------------
#define ASTR 40
#define BSTR 40
__global__ __launch_bounds__(256) void gemm_bf16_kernel(
    const float* __restrict__ Ag, const unsigned short* __restrict__ Wt,
    unsigned short* __restrict__ Cg, const float* __restrict__ bias,
    int M, int K, int Kpad, int Ncol) {
  __shared__ unsigned short As[64 * ASTR];
  __shared__ unsigned short Bs[256 * BSTR];
  int t = threadIdx.x;
  int lane = t & 63;
  int wid = t >> 6;
  int quad = lane >> 4;
  int l16 = lane & 15;
  int rowBase = blockIdx.x * 64;
  int nbase = wid * 64;

  floatx4 acc[4][4];
#pragma unroll
  for (int i = 0; i < 4; ++i)
#pragma unroll
    for (int j = 0; j < 4; ++j) acc[i][j] = (floatx4){0.f, 0.f, 0.f, 0.f};

  int ar = t >> 2;
  int ac = (t & 3) * 8;
  long gm = rowBase + ar;
  bool rowOK = (gm < M);
  const float* aRow = Ag + gm * (long)K;
  const unsigned short* wRow = Wt + (long)t * Kpad;

  float va[8];
  int4 vb[4];

  auto loadA = [&](int k0) {
    if (rowOK && (k0 + 32 <= K)) {
      const float* ap = aRow + k0 + ac;
      float2 f0 = *(const float2*)(ap + 0);
      float2 f1 = *(const float2*)(ap + 2);
      float2 f2 = *(const float2*)(ap + 4);
      float2 f3 = *(const float2*)(ap + 6);
      va[0] = f0.x; va[1] = f0.y; va[2] = f1.x; va[3] = f1.y;
      va[4] = f2.x; va[5] = f2.y; va[6] = f3.x; va[7] = f3.y;
    } else {
#pragma unroll
      for (int u = 0; u < 8; ++u) {
        int kk = k0 + ac + u;
        va[u] = (rowOK && kk < K) ? aRow[kk] : 0.f;
      }
    }
  };
  auto loadB = [&](int k0) {
    const int4* src = (const int4*)(wRow + k0);
    vb[0] = src[0]; vb[1] = src[1]; vb[2] = src[2]; vb[3] = src[3];
  };

  int KT = Kpad / 32;
  loadA(0);
  loadB(0);

  for (int kt = 0; kt < KT; ++kt) {
    // drain prefetched regs into LDS
    __hip_bfloat162* adst = (__hip_bfloat162*)&As[ar * ASTR + ac];
#pragma unroll
    for (int u = 0; u < 4; ++u)
      adst[u] = __hip_bfloat162(__float2bfloat16(va[2 * u]), __float2bfloat16(va[2 * u + 1]));
    {
      int4* dst = (int4*)&Bs[t * BSTR];
      dst[0] = vb[0]; dst[1] = vb[1]; dst[2] = vb[2]; dst[3] = vb[3];
    }
    __syncthreads();

    short8 af[4], bfr[4];
#pragma unroll
    for (int i = 0; i < 4; ++i)
      af[i] = *(const short8*)&As[(i * 16 + l16) * ASTR + quad * 8];
#pragma unroll
    for (int j = 0; j < 4; ++j)
      bfr[j] = *(const short8*)&Bs[(nbase + j * 16 + l16) * BSTR + quad * 8];

    // issue next tile's global loads BEFORE the MFMAs (overlap)
    if (kt + 1 < KT) {
      int k0 = (kt + 1) * 32;
      loadA(k0);
      loadB(k0);
    }

#pragma unroll
    for (int i = 0; i < 4; ++i)
#pragma unroll
      for (int j = 0; j < 4; ++j)
        acc[i][j] = __builtin_amdgcn_mfma_f32_16x16x32_bf16(af[i], bfr[j], acc[i][j], 0, 0, 0);
    __syncthreads();
  }

#pragma unroll
  for (int j = 0; j < 4; ++j) {
    int gn = nbase + j * 16 + l16;
    if (gn >= Ncol) continue;
    float bv = bias ? bias[gn] : 0.f;
#pragma unroll
    for (int i = 0; i < 4; ++i) {
      int gm0 = rowBase + i * 16 + quad * 4;
#pragma unroll
      for (int r = 0; r < 4; ++r) {
        int gmm = gm0 + r;
        if (gmm < M) Cg[(long)gmm * Ncol + gn] = f2bf(acc[i][j][r] + bv);
      }
    }
  }
}

// ---------------------------------------------------------------------------
// Aggregation (bf16 XR): one wave per dst, lane pair-of-h; half-waves split edges.
// ---------------------------------------------------------------------------
__global__ __launch_bounds__(256) void agg_kernel(const unsigned short* __restrict__ XR,
                                                  const int* __restrict__ offs,
                                                  const int* __restrict__ srcs,
                                                  const float* __restrict__ bias,
                                                  const float* __restrict__ lng,
                                                  const float* __restrict__ lnb,
                                                  float* __restrict__ out, int mode) {
  int lane = threadIdx.x & 63;
  int wid = threadIdx.x >> 6;
  int half = lane >> 5;
  int l = lane & 31;
  int dst = blockIdx.x * 4 + wid;
  if (dst >= Nn) return;

  __hip_bfloat162 rt = *(const __hip_bfloat162*)&XR[(long)dst * 256 + 192 + 2 * l];
  float2 bv = *(const float2*)&bias[2 * l];
  float tx = __bfloat162float(rt.x) + bv.x;
  float ty = __bfloat162float(rt.y) + bv.y;

#pragma unroll
  for (int r = 0; r < RR; ++r) {
    int s = r * Nn + dst;
    int beg = offs[s], end = offs[s + 1];
    float ax = 0.f, ay = 0.f;
    for (int e = beg + half; e < end; e += 2) {
      int src = srcs[e];
      __hip_bfloat162 m = *(const __hip_bfloat162*)&XR[(long)src * 256 + r * 64 + 2 * l];
      ax += __bfloat162float(m.x);
      ay += __bfloat162float(m.y);
    }
    ax += __shfl_xor(ax, 32, 64);
    ay += __shfl_xor(ay, 32, 64);
    int cnt = end - beg;
    if (cnt > 0) {
      float inv = 1.f / (float)cnt;
      tx += ax * inv;
      ty += ay * inv;
    }
  }

  if (mode == 0) {
    if (half == 0) {
      float2 o;
      o.x = fmaxf(tx, 0.f);
      o.y = fmaxf(ty, 0.f);
      *(float2*)&out[(long)dst * 64 + 2 * l] = o;
    }
  } else {
    float s = tx + ty;
#pragma unroll
    for (int m = 1; m < 32; m <<= 1) s += __shfl_xor(s, m, 64);
    float mu = s * (1.f / 64.f);
    float dx = tx - mu, dy = ty - mu;
    float vv = dx * dx + dy * dy;
#pragma unroll
    for (int m = 1; m < 32; m <<= 1) vv += __shfl_xor(vv, m, 64);
    float rstd = rsqrtf(vv * (1.f / 64.f) + 1e-5f);
    if (half == 0) {
      float2 g = *(const float2*)&lng[2 * l];
      float2 b2 = *(const float2*)&lnb[2 * l];
      float2 o;
      o.x = dx * rstd * g.x + b2.x;
      o.y = dy * rstd * g.y + b2.y;
      *(float2*)&out[(long)dst * 64 + 2 * l] = o;
    }
  }
}

// ---------------------------------------------------------------------------
// Edge head: ONE THREAD PER EDGE (serial dots, scalar ew2, own log-softmax).
// ---------------------------------------------------------------------------
__global__ __launch_bounds__(256) void edge_head_kernel(const unsigned short* __restrict__ AB,
                                                        const int* __restrict__ ei,
                                                        const float* __restrict__ ew2,
                                                        const float* __restrict__ eb2,
                                                        float* __restrict__ out) {
  long e = (long)blockIdx.x * 256 + threadIdx.x;
  if (e >= Ee) return;
  int row = ei[e];
  int col = ei[Ee + e];
  const int4* pa = (const int4*)&AB[(long)row * 128];
  const int4* pb = (const int4*)&AB[(long)col * 128 + 64];
  float acc0 = 0.f, acc1 = 0.f, acc2 = 0.f;
#pragma unroll
  for (int q = 0; q < 8; ++q) {
    int4 av = pa[q];
    int4 bv = pb[q];
    const int* ad = (const int*)&av;
    const int* bd = (const int*)&bv;
#pragma unroll
    for (int d = 0; d < 4; ++d) {
      int A = ad[d], B = bd[d];
      float a0 = __int_as_float(A << 16);
      float a1 = __int_as_float(A & 0xffff0000);
      float b0 = __int_as_float(B << 16);
      float b1 = __int_as_float(B & 0xffff0000);
      float e0 = fmaxf(a0 + b0, 0.f);
      float e1 = fmaxf(a1 + b1, 0.f);
      int h = q * 8 + d * 2;
      acc0 = fmaf(e0, ew2[h * 3 + 0], acc0);
      acc1 = fmaf(e0, ew2[h * 3 + 1], acc1);
      acc2 = fmaf(e0, ew2[h * 3 + 2], acc2);
      acc0 = fmaf(e1, ew2[h * 3 + 3], acc0);
      acc1 = fmaf(e1, ew2[h * 3 + 4], acc1);
      acc2 = fmaf(e1, ew2[h * 3 + 5], acc2);
    }
  }
  float l0 = acc0 + eb2[0], l1 = acc1 + eb2[1], l2 = acc2 + eb2[2];
  float mx = fmaxf(l0, fmaxf(l1, l2));
  float ls = mx + logf(expf(l0 - mx) + expf(l1 - mx) + expf(l2 - mx));
  out[e * 3 + 0] = l0 - ls;
  out[e * 3 + 1] = l1 - ls;
  out[e * 3 + 2] = l2 - ls;
}

// ---------------------------------------------------------------------------
// Node head: one thread per node (x3 fp32).
// ---------------------------------------------------------------------------
__global__ __launch_bounds__(256) void node_head_kernel(const float* __restrict__ x3,
                                                        const float* __restrict__ nw1,
                                                        const float* __restrict__ nb1,
                                                        const float* __restrict__ nw2,
                                                        const float* __restrict__ nb2,
                                                        float* __restrict__ out) {
  __shared__ float w1s[64 * 32];
  __shared__ float w2s[64];
  for (int i = threadIdx.x; i < 2048; i += 256) w1s[i] = nw1[i];
  if (threadIdx.x < 64) w2s[threadIdx.x] = nw2[threadIdx.x];
  __syncthreads();
  int n = blockIdx.x * 256 + threadIdx.x;
  if (n >= Nn) return;
  float acc[32];
#pragma unroll
  for (int c = 0; c < 32; ++c) acc[c] = nb1[c];
  for (int k = 0; k < 64; ++k) {
    float xv = x3[(long)n * 64 + k];
#pragma unroll
    for (int c = 0; c < 32; ++c) acc[c] += xv * w1s[k * 32 + c];
  }
  float l0 = nb2[0], l1 = nb2[1];
#pragma unroll
  for (int c = 0; c < 32; ++c) {
    float h = fmaxf(acc[c], 0.f);
    l0 += h * w2s[c * 2 + 0];
    l1 += h * w2s[c * 2 + 1];
  }
  float mx = fmaxf(l0, l1);
  float ls = mx + logf(expf(l0 - mx) + expf(l1 - mx));
  out[(long)3 * Ee + (long)n * 2 + 0] = l0 - ls;
  out[(long)3 * Ee + (long)n * 2 + 1] = l1 - ls;
}

// ---------------------------------------------------------------------------
extern "C" void kernel_launch(void* const* d_in, const int* in_sizes, int n_in,
                              void* d_out, int out_size, void* d_ws, size_t ws_size,
                              hipStream_t stream) {
  const float* x = (const float*)d_in[0];
  const int* ei = (const int*)d_in[1];
  const int* et = (const int*)d_in[2];
  const float* W1 = (const float*)d_in[3];
  const float* root1 = (const float*)d_in[4];
  const float* b1 = (const float*)d_in[5];
  const float* W2 = (const float*)d_in[6];
  const float* root2 = (const float*)d_in[7];
  const float* b2 = (const float*)d_in[8];
  const float* W3 = (const float*)d_in[9];
  const float* root3 = (const float*)d_in[10];
  const float* b3 = (const float*)d_in[11];
  const float* lng = (const float*)d_in[12];
  const float* lnb = (const float*)d_in[13];
  const float* ew1 = (const float*)d_in[14];
  const float* eb1 = (const float*)d_in[15];
  const float* ew2 = (const float*)d_in[16];
  const float* eb2 = (const float*)d_in[17];
  const float* nw1 = (const float*)d_in[18];
  const float* nb1 = (const float*)d_in[19];
  const float* nw2 = (const float*)d_in[20];
  const float* nb2 = (const float*)d_in[21];
  float* out = (float*)d_out;

  char* p = (char*)d_ws;
  size_t off = 0;
  auto alloc = [&](size_t bytes) {
    void* r = p + off;
    off += (bytes + 255) & ~(size_t)255;
    return r;
  };
  unsigned short* XR = (unsigned short*)alloc((size_t)Nn * 256 * 2);  // bf16; also AB
  float* xA = (float*)alloc((size_t)Nn * 64 * 4);
  float* xB = (float*)alloc((size_t)Nn * 64 * 4);
  int* srcs = (int*)alloc((size_t)Ee * 4);
  int* offs = (int*)alloc((size_t)(RN + 1) * 4);
  int* cursor = (int*)alloc((size_t)RN * 4);
  int* bsums = (int*)alloc(1024);
  unsigned short* Wt1 = (unsigned short*)alloc((size_t)256 * KPAD1 * 2);
  unsigned short* Wt2 = (unsigned short*)alloc((size_t)256 * 64 * 2);
  unsigned short* Wt3 = (unsigned short*)alloc((size_t)256 * 64 * 2);
  unsigned short* Wth = (unsigned short*)alloc((size_t)256 * 64 * 2);
  float* biasH = (float*)alloc(128 * 4);

  int nb = (RN + 1023) / 1024;  // 147

  // --- CSR build ---
  hipMemsetAsync(cursor, 0, (size_t)RN * 4, stream);
  count_kernel<<<(Ee + 255) / 256, 256, 0, stream>>>(ei, et, cursor);
  scan1_kernel<<<nb, 256, 0, stream>>>(cursor, offs, bsums, RN);
  scan_top_kernel<<<1, 256, 0, stream>>>(bsums, nb);
  scan_add_kernel<<<(RN + 256) / 256 + 1, 256, 0, stream>>>(offs, bsums, RN);
  hipMemsetAsync(cursor, 0, (size_t)RN * 4, stream);
  fill_kernel<<<(Ee + 255) / 256, 256, 0, stream>>>(ei, et, offs, cursor, srcs);

  // --- weight prep (bf16 transposed) ---
  prep_wt_kernel<<<(256 * KPAD1 + 255) / 256, 256, 0, stream>>>(W1, root1, Wt1, FIN, KPAD1);
  prep_wt_kernel<<<(256 * 64 + 255) / 256, 256, 0, stream>>>(W2, root2, Wt2, 64, 64);
  prep_wt_kernel<<<(256 * 64 + 255) / 256, 256, 0, stream>>>(W3, root3, Wt3, 64, 64);
  prep_wth_kernel<<<(256 * 64 + 255) / 256, 256, 0, stream>>>(ew1, eb1, Wth, biasH);

  int gemmBlocks = (Nn + 63) / 64;  // 782
  int aggBlocks = (Nn + 3) / 4;

  // --- layer 1 ---
  gemm_bf16_kernel<<<gemmBlocks, 256, 0, stream>>>(x, Wt1, XR, nullptr, Nn, FIN, KPAD1, 256);
  agg_kernel<<<aggBlocks, 256, 0, stream>>>(XR, offs, srcs, b1, nullptr, nullptr, xA, 0);
  // --- layer 2 ---
  gemm_bf16_kernel<<<gemmBlocks, 256, 0, stream>>>(xA, Wt2, XR, nullptr, Nn, 64, 64, 256);
  agg_kernel<<<aggBlocks, 256, 0, stream>>>(XR, offs, srcs, b2, nullptr, nullptr, xB, 0);
  // --- layer 3 + layernorm ---
  gemm_bf16_kernel<<<gemmBlocks, 256, 0, stream>>>(xB, Wt3, XR, nullptr, Nn, 64, 64, 256);
  agg_kernel<<<aggBlocks, 256, 0, stream>>>(XR, offs, srcs, b3, lng, lnb, xA, 1);

  // --- heads ---
  gemm_bf16_kernel<<<gemmBlocks, 256, 0, stream>>>(xA, Wth, XR, biasH, Nn, 64, 64, 128);
  edge_head_kernel<<<(Ee + 255) / 256, 256, 0, stream>>>(XR, ei, ew2, eb2, out);
  node_head_kernel<<<(Nn + 255) / 256, 256, 0, stream>>>(xA, nw1, nb1, nw2, nb2, out);
}

// Round 5
// 929.300 us; speedup vs baseline: 1.1130x; 1.1130x over previous
//
#include <hip/hip_runtime.h>
#include <hip/hip_bf16.h>
#include <math.h>

#define Nn 50000
#define Ee 1600000
#define RR 3
#define RN (RR * Nn)
#define FIN 770
#define KPAD1 800

typedef __attribute__((ext_vector_type(8))) short short8;
typedef __attribute__((ext_vector_type(4))) float floatx4;

static __device__ __forceinline__ unsigned short f2bf(float v) {
  __hip_bfloat16 h = __float2bfloat16(v);
  return *(unsigned short*)&h;
}

// ---------------------------------------------------------------------------
// CSR build: counts -> exclusive scan -> fill (edge list identical all layers)
// ---------------------------------------------------------------------------
__global__ __launch_bounds__(256) void count_kernel(const int* __restrict__ ei,
                                                    const int* __restrict__ et,
                                                    int* __restrict__ counts) {
  int e = blockIdx.x * 256 + threadIdx.x;
  if (e >= Ee) return;
  int col = ei[Ee + e];
  int r = et[e];
  atomicAdd(&counts[r * Nn + col], 1);
}

__global__ __launch_bounds__(256) void scan1_kernel(const int* __restrict__ counts,
                                                    int* __restrict__ offs,
                                                    int* __restrict__ bsums, int n) {
  __shared__ int sh[256];
  int t = threadIdx.x;
  int base = blockIdx.x * 1024 + t * 4;
  int v0 = (base + 0 < n) ? counts[base + 0] : 0;
  int v1 = (base + 1 < n) ? counts[base + 1] : 0;
  int v2 = (base + 2 < n) ? counts[base + 2] : 0;
  int v3 = (base + 3 < n) ? counts[base + 3] : 0;
  int tot = v0 + v1 + v2 + v3;
  sh[t] = tot;
  __syncthreads();
  for (int off = 1; off < 256; off <<= 1) {
    int v = (t >= off) ? sh[t - off] : 0;
    __syncthreads();
    sh[t] += v;
    __syncthreads();
  }
  int run = sh[t] - tot;
  if (base + 0 < n) offs[base + 0] = run; run += v0;
  if (base + 1 < n) offs[base + 1] = run; run += v1;
  if (base + 2 < n) offs[base + 2] = run; run += v2;
  if (base + 3 < n) offs[base + 3] = run;
  if (t == 255) bsums[blockIdx.x] = sh[255];
}

__global__ __launch_bounds__(256) void scan_top_kernel(int* __restrict__ bsums, int nb) {
  __shared__ int sh[256];
  int t = threadIdx.x;
  int v = (t < nb) ? bsums[t] : 0;
  sh[t] = v;
  __syncthreads();
  for (int off = 1; off < 256; off <<= 1) {
    int x = (t >= off) ? sh[t - off] : 0;
    __syncthreads();
    sh[t] += x;
    __syncthreads();
  }
  if (t < nb) bsums[t] = sh[t] - v;
}

__global__ __launch_bounds__(256) void scan_add_kernel(int* __restrict__ offs,
                                                       const int* __restrict__ bsums,
                                                       int n) {
  int i = blockIdx.x * 256 + threadIdx.x;
  if (i > n) return;
  if (i == n) { offs[n] = Ee; return; }
  offs[i] += bsums[i >> 10];
}

__global__ __launch_bounds__(256) void fill_kernel(const int* __restrict__ ei,
                                                   const int* __restrict__ et,
                                                   const int* __restrict__ offs,
                                                   int* __restrict__ cursor,
                                                   int* __restrict__ srcs) {
  int e = blockIdx.x * 256 + threadIdx.x;
  if (e >= Ee) return;
  int row = ei[e];
  int col = ei[Ee + e];
  int r = et[e];
  int s = r * Nn + col;
  int pos = offs[s] + atomicAdd(&cursor[s], 1);
  srcs[pos] = row;
}

// ---------------------------------------------------------------------------
// Weight prep: Wt (bf16, n-major) [256][Kpad]; cols 0..191 = W[r], 192..255 = root
// ---------------------------------------------------------------------------
__global__ __launch_bounds__(256) void prep_wt_kernel(const float* __restrict__ W,
                                                      const float* __restrict__ root,
                                                      unsigned short* __restrict__ Wt,
                                                      int K, int Kpad) {
  int i = blockIdx.x * 256 + threadIdx.x;
  if (i >= 256 * Kpad) return;
  int c = i / Kpad, k = i % Kpad;
  float v = 0.f;
  if (k < K) {
    if (c < 192) {
      int r = c >> 6, h = c & 63;
      v = W[((long)r * K + k) * 64 + h];
    } else {
      v = root[k * 64 + (c - 192)];
    }
  }
  Wt[i] = f2bf(v);
}

// head weights: Wt_h [256][64] bf16 (rows 128..255 zero), biasH[128] fp32
__global__ __launch_bounds__(256) void prep_wth_kernel(const float* __restrict__ ew1,
                                                       const float* __restrict__ eb1,
                                                       unsigned short* __restrict__ Wth,
                                                       float* __restrict__ biasH) {
  int i = blockIdx.x * 256 + threadIdx.x;
  if (i < 128) biasH[i] = (i < 64) ? eb1[i] : 0.f;
  if (i >= 256 * 64) return;
  int c = i >> 6, k = i & 63;
  float v = 0.f;
  if (c < 64) v = ew1[k * 64 + c];
  else if (c < 128) v = ew1[(64 + k) * 64 + (c - 64)];
  Wth[i] = f2bf(v);
}

// ---------------------------------------------------------------------------
// bf16 MFMA GEMM, register-prefetch pipelined (explicit scalars — NO arrays,
// NO lambdas: R4's array/lambda version was demoted to scratch, +150MB HBM).
// tile 64x256, BK=32, 4 waves; each wave 64x64 via 4x4 of 16x16x32 MFMA.
// Next tile's global loads issue right after the barrier, before ds_reads;
// vmcnt-wait lands at next iteration's LDS store.
// ---------------------------------------------------------------------------
#define ASTR 40
#define BSTR 40

#define LOAD_A_FULL(k0)                                        \
  {                                                            \
    const float* ap = aRow + (k0) + ac;                        \
    a01 = *(const float4*)(ap + 0);                            \
    a23 = *(const float4*)(ap + 4);                            \
  }
#define LOAD_A_MASK(k0)                                        \
  {                                                            \
    int kb = (k0) + ac;                                        \
    a01.x = (rowOK && kb + 0 < K) ? aRow[kb + 0] : 0.f;        \
    a01.y = (rowOK && kb + 1 < K) ? aRow[kb + 1] : 0.f;        \
    a01.z = (rowOK && kb + 2 < K) ? aRow[kb + 2] : 0.f;        \
    a01.w = (rowOK && kb + 3 < K) ? aRow[kb + 3] : 0.f;        \
    a23.x = (rowOK && kb + 4 < K) ? aRow[kb + 4] : 0.f;        \
    a23.y = (rowOK && kb + 5 < K) ? aRow[kb + 5] : 0.f;        \
    a23.z = (rowOK && kb + 6 < K) ? aRow[kb + 6] : 0.f;        \
    a23.w = (rowOK && kb + 7 < K) ? aRow[kb + 7] : 0.f;        \
  }
#define LOAD_A(k0)                                             \
  if (rowOK && (k0) + 32 <= K) LOAD_A_FULL(k0) else LOAD_A_MASK(k0)
#define LOAD_B(k0)                                             \
  {                                                            \
    const int4* srcp = (const int4*)(wRow + (k0));             \
    b0 = srcp[0]; b1 = srcp[1]; b2 = srcp[2]; b3 = srcp[3];    \
  }
#define STORE_TILE()                                                          \
  {                                                                           \
    __hip_bfloat162* adst = (__hip_bfloat162*)&As[ar * ASTR + ac];            \
    adst[0] = __hip_bfloat162(__float2bfloat16(a01.x), __float2bfloat16(a01.y)); \
    adst[1] = __hip_bfloat162(__float2bfloat16(a01.z), __float2bfloat16(a01.w)); \
    adst[2] = __hip_bfloat162(__float2bfloat16(a23.x), __float2bfloat16(a23.y)); \
    adst[3] = __hip_bfloat162(__float2bfloat16(a23.z), __float2bfloat16(a23.w)); \
    int4* bdst = (int4*)&Bs[t * BSTR];                                        \
    bdst[0] = b0; bdst[1] = b1; bdst[2] = b2; bdst[3] = b3;                   \
  }

__global__ __launch_bounds__(256) void gemm_bf16_kernel(
    const float* __restrict__ Ag, const unsigned short* __restrict__ Wt,
    unsigned short* __restrict__ Cg, const float* __restrict__ bias,
    int M, int K, int Kpad, int Ncol) {
  __shared__ unsigned short As[64 * ASTR];
  __shared__ unsigned short Bs[256 * BSTR];
  int t = threadIdx.x;
  int lane = t & 63;
  int wid = t >> 6;
  int quad = lane >> 4;
  int l16 = lane & 15;
  int rowBase = blockIdx.x * 64;
  int nbase = wid * 64;

  floatx4 acc[4][4];
#pragma unroll
  for (int i = 0; i < 4; ++i)
#pragma unroll
    for (int j = 0; j < 4; ++j) acc[i][j] = (floatx4){0.f, 0.f, 0.f, 0.f};

  int ar = t >> 2;
  int ac = (t & 3) * 8;
  long gm = rowBase + ar;
  bool rowOK = (gm < M);
  const float* aRow = Ag + gm * (long)K;
  const unsigned short* wRow = Wt + (long)t * Kpad;

  float4 a01, a23;   // prefetched A (8 fp32)
  int4 b0, b1, b2, b3;  // prefetched B (32 bf16)

  int KT = Kpad / 32;
  LOAD_A(0);
  LOAD_B(0);

  for (int kt = 0; kt < KT; ++kt) {
    STORE_TILE();
    __syncthreads();

    // issue next tile's global loads FIRST (overlap with ds_read + MFMA)
    if (kt + 1 < KT) {
      int k0n = (kt + 1) * 32;
      LOAD_A(k0n);
      LOAD_B(k0n);
    }

    short8 af[4], bfr[4];
#pragma unroll
    for (int i = 0; i < 4; ++i)
      af[i] = *(const short8*)&As[(i * 16 + l16) * ASTR + quad * 8];
#pragma unroll
    for (int j = 0; j < 4; ++j)
      bfr[j] = *(const short8*)&Bs[(nbase + j * 16 + l16) * BSTR + quad * 8];

#pragma unroll
    for (int i = 0; i < 4; ++i)
#pragma unroll
      for (int j = 0; j < 4; ++j)
        acc[i][j] = __builtin_amdgcn_mfma_f32_16x16x32_bf16(af[i], bfr[j], acc[i][j], 0, 0, 0);
    __syncthreads();
  }

#pragma unroll
  for (int j = 0; j < 4; ++j) {
    int gn = nbase + j * 16 + l16;
    if (gn >= Ncol) continue;
    float bv = bias ? bias[gn] : 0.f;
#pragma unroll
    for (int i = 0; i < 4; ++i) {
      int gm0 = rowBase + i * 16 + quad * 4;
#pragma unroll
      for (int r = 0; r < 4; ++r) {
        int gmm = gm0 + r;
        if (gmm < M) Cg[(long)gmm * Ncol + gn] = f2bf(acc[i][j][r] + bv);
      }
    }
  }
}

// ---------------------------------------------------------------------------
// Aggregation (bf16 XR): one wave per dst, lane pair-of-h; half-waves split edges.
// ---------------------------------------------------------------------------
__global__ __launch_bounds__(256) void agg_kernel(const unsigned short* __restrict__ XR,
                                                  const int* __restrict__ offs,
                                                  const int* __restrict__ srcs,
                                                  const float* __restrict__ bias,
                                                  const float* __restrict__ lng,
                                                  const float* __restrict__ lnb,
                                                  float* __restrict__ out, int mode) {
  int lane = threadIdx.x & 63;
  int wid = threadIdx.x >> 6;
  int half = lane >> 5;
  int l = lane & 31;
  int dst = blockIdx.x * 4 + wid;
  if (dst >= Nn) return;

  __hip_bfloat162 rt = *(const __hip_bfloat162*)&XR[(long)dst * 256 + 192 + 2 * l];
  float2 bv = *(const float2*)&bias[2 * l];
  float tx = __bfloat162float(rt.x) + bv.x;
  float ty = __bfloat162float(rt.y) + bv.y;

#pragma unroll
  for (int r = 0; r < RR; ++r) {
    int s = r * Nn + dst;
    int beg = offs[s], end = offs[s + 1];
    float ax = 0.f, ay = 0.f;
    for (int e = beg + half; e < end; e += 2) {
      int src = srcs[e];
      __hip_bfloat162 m = *(const __hip_bfloat162*)&XR[(long)src * 256 + r * 64 + 2 * l];
      ax += __bfloat162float(m.x);
      ay += __bfloat162float(m.y);
    }
    ax += __shfl_xor(ax, 32, 64);
    ay += __shfl_xor(ay, 32, 64);
    int cnt = end - beg;
    if (cnt > 0) {
      float inv = 1.f / (float)cnt;
      tx += ax * inv;
      ty += ay * inv;
    }
  }

  if (mode == 0) {
    if (half == 0) {
      float2 o;
      o.x = fmaxf(tx, 0.f);
      o.y = fmaxf(ty, 0.f);
      *(float2*)&out[(long)dst * 64 + 2 * l] = o;
    }
  } else {
    float s = tx + ty;
#pragma unroll
    for (int m = 1; m < 32; m <<= 1) s += __shfl_xor(s, m, 64);
    float mu = s * (1.f / 64.f);
    float dx = tx - mu, dy = ty - mu;
    float vv = dx * dx + dy * dy;
#pragma unroll
    for (int m = 1; m < 32; m <<= 1) vv += __shfl_xor(vv, m, 64);
    float rstd = rsqrtf(vv * (1.f / 64.f) + 1e-5f);
    if (half == 0) {
      float2 g = *(const float2*)&lng[2 * l];
      float2 b2 = *(const float2*)&lnb[2 * l];
      float2 o;
      o.x = dx * rstd * g.x + b2.x;
      o.y = dy * rstd * g.y + b2.y;
      *(float2*)&out[(long)dst * 64 + 2 * l] = o;
    }
  }
}

// ---------------------------------------------------------------------------
// Edge head: ONE THREAD PER EDGE (serial dots, scalar ew2, own log-softmax).
// ---------------------------------------------------------------------------
__global__ __launch_bounds__(256) void edge_head_kernel(const unsigned short* __restrict__ AB,
                                                        const int* __restrict__ ei,
                                                        const float* __restrict__ ew2,
                                                        const float* __restrict__ eb2,
                                                        float* __restrict__ out) {
  long e = (long)blockIdx.x * 256 + threadIdx.x;
  if (e >= Ee) return;
  int row = ei[e];
  int col = ei[Ee + e];
  const int4* pa = (const int4*)&AB[(long)row * 128];
  const int4* pb = (const int4*)&AB[(long)col * 128 + 64];
  float acc0 = 0.f, acc1 = 0.f, acc2 = 0.f;
#pragma unroll
  for (int q = 0; q < 8; ++q) {
    int4 av = pa[q];
    int4 bv = pb[q];
    const int* ad = (const int*)&av;
    const int* bd = (const int*)&bv;
#pragma unroll
    for (int d = 0; d < 4; ++d) {
      int A = ad[d], B = bd[d];
      float a0 = __int_as_float(A << 16);
      float a1 = __int_as_float(A & 0xffff0000);
      float b0 = __int_as_float(B << 16);
      float b1 = __int_as_float(B & 0xffff0000);
      float e0 = fmaxf(a0 + b0, 0.f);
      float e1 = fmaxf(a1 + b1, 0.f);
      int h = q * 8 + d * 2;
      acc0 = fmaf(e0, ew2[h * 3 + 0], acc0);
      acc1 = fmaf(e0, ew2[h * 3 + 1], acc1);
      acc2 = fmaf(e0, ew2[h * 3 + 2], acc2);
      acc0 = fmaf(e1, ew2[h * 3 + 3], acc0);
      acc1 = fmaf(e1, ew2[h * 3 + 4], acc1);
      acc2 = fmaf(e1, ew2[h * 3 + 5], acc2);
    }
  }
  float l0 = acc0 + eb2[0], l1 = acc1 + eb2[1], l2 = acc2 + eb2[2];
  float mx = fmaxf(l0, fmaxf(l1, l2));
  float ls = mx + logf(expf(l0 - mx) + expf(l1 - mx) + expf(l2 - mx));
  out[e * 3 + 0] = l0 - ls;
  out[e * 3 + 1] = l1 - ls;
  out[e * 3 + 2] = l2 - ls;
}

// ---------------------------------------------------------------------------
// Node head: one thread per node (x3 fp32).
// ---------------------------------------------------------------------------
__global__ __launch_bounds__(256) void node_head_kernel(const float* __restrict__ x3,
                                                        const float* __restrict__ nw1,
                                                        const float* __restrict__ nb1,
                                                        const float* __restrict__ nw2,
                                                        const float* __restrict__ nb2,
                                                        float* __restrict__ out) {
  __shared__ float w1s[64 * 32];
  __shared__ float w2s[64];
  for (int i = threadIdx.x; i < 2048; i += 256) w1s[i] = nw1[i];
  if (threadIdx.x < 64) w2s[threadIdx.x] = nw2[threadIdx.x];
  __syncthreads();
  int n = blockIdx.x * 256 + threadIdx.x;
  if (n >= Nn) return;
  float acc[32];
#pragma unroll
  for (int c = 0; c < 32; ++c) acc[c] = nb1[c];
  for (int k = 0; k < 64; ++k) {
    float xv = x3[(long)n * 64 + k];
#pragma unroll
    for (int c = 0; c < 32; ++c) acc[c] += xv * w1s[k * 32 + c];
  }
  float l0 = nb2[0], l1 = nb2[1];
#pragma unroll
  for (int c = 0; c < 32; ++c) {
    float h = fmaxf(acc[c], 0.f);
    l0 += h * w2s[c * 2 + 0];
    l1 += h * w2s[c * 2 + 1];
  }
  float mx = fmaxf(l0, l1);
  float ls = mx + logf(expf(l0 - mx) + expf(l1 - mx));
  out[(long)3 * Ee + (long)n * 2 + 0] = l0 - ls;
  out[(long)3 * Ee + (long)n * 2 + 1] = l1 - ls;
}

// ---------------------------------------------------------------------------
extern "C" void kernel_launch(void* const* d_in, const int* in_sizes, int n_in,
                              void* d_out, int out_size, void* d_ws, size_t ws_size,
                              hipStream_t stream) {
  const float* x = (const float*)d_in[0];
  const int* ei = (const int*)d_in[1];
  const int* et = (const int*)d_in[2];
  const float* W1 = (const float*)d_in[3];
  const float* root1 = (const float*)d_in[4];
  const float* b1 = (const float*)d_in[5];
  const float* W2 = (const float*)d_in[6];
  const float* root2 = (const float*)d_in[7];
  const float* b2 = (const float*)d_in[8];
  const float* W3 = (const float*)d_in[9];
  const float* root3 = (const float*)d_in[10];
  const float* b3 = (const float*)d_in[11];
  const float* lng = (const float*)d_in[12];
  const float* lnb = (const float*)d_in[13];
  const float* ew1 = (const float*)d_in[14];
  const float* eb1 = (const float*)d_in[15];
  const float* ew2 = (const float*)d_in[16];
  const float* eb2 = (const float*)d_in[17];
  const float* nw1 = (const float*)d_in[18];
  const float* nb1 = (const float*)d_in[19];
  const float* nw2 = (const float*)d_in[20];
  const float* nb2 = (const float*)d_in[21];
  float* out = (float*)d_out;

  char* p = (char*)d_ws;
  size_t off = 0;
  auto alloc = [&](size_t bytes) {
    void* r = p + off;
    off += (bytes + 255) & ~(size_t)255;
    return r;
  };
  unsigned short* XR = (unsigned short*)alloc((size_t)Nn * 256 * 2);  // bf16; also AB
  float* xA = (float*)alloc((size_t)Nn * 64 * 4);
  float* xB = (float*)alloc((size_t)Nn * 64 * 4);
  int* srcs = (int*)alloc((size_t)Ee * 4);
  int* offs = (int*)alloc((size_t)(RN + 1) * 4);
  int* cursor = (int*)alloc((size_t)RN * 4);
  int* bsums = (int*)alloc(1024);
  unsigned short* Wt1 = (unsigned short*)alloc((size_t)256 * KPAD1 * 2);
  unsigned short* Wt2 = (unsigned short*)alloc((size_t)256 * 64 * 2);
  unsigned short* Wt3 = (unsigned short*)alloc((size_t)256 * 64 * 2);
  unsigned short* Wth = (unsigned short*)alloc((size_t)256 * 64 * 2);
  float* biasH = (float*)alloc(128 * 4);

  int nb = (RN + 1023) / 1024;  // 147

  // --- CSR build ---
  hipMemsetAsync(cursor, 0, (size_t)RN * 4, stream);
  count_kernel<<<(Ee + 255) / 256, 256, 0, stream>>>(ei, et, cursor);
  scan1_kernel<<<nb, 256, 0, stream>>>(cursor, offs, bsums, RN);
  scan_top_kernel<<<1, 256, 0, stream>>>(bsums, nb);
  scan_add_kernel<<<(RN + 256) / 256 + 1, 256, 0, stream>>>(offs, bsums, RN);
  hipMemsetAsync(cursor, 0, (size_t)RN * 4, stream);
  fill_kernel<<<(Ee + 255) / 256, 256, 0, stream>>>(ei, et, offs, cursor, srcs);

  // --- weight prep (bf16 transposed) ---
  prep_wt_kernel<<<(256 * KPAD1 + 255) / 256, 256, 0, stream>>>(W1, root1, Wt1, FIN, KPAD1);
  prep_wt_kernel<<<(256 * 64 + 255) / 256, 256, 0, stream>>>(W2, root2, Wt2, 64, 64);
  prep_wt_kernel<<<(256 * 64 + 255) / 256, 256, 0, stream>>>(W3, root3, Wt3, 64, 64);
  prep_wth_kernel<<<(256 * 64 + 255) / 256, 256, 0, stream>>>(ew1, eb1, Wth, biasH);

  int gemmBlocks = (Nn + 63) / 64;  // 782
  int aggBlocks = (Nn + 3) / 4;

  // --- layer 1 ---
  gemm_bf16_kernel<<<gemmBlocks, 256, 0, stream>>>(x, Wt1, XR, nullptr, Nn, FIN, KPAD1, 256);
  agg_kernel<<<aggBlocks, 256, 0, stream>>>(XR, offs, srcs, b1, nullptr, nullptr, xA, 0);
  // --- layer 2 ---
  gemm_bf16_kernel<<<gemmBlocks, 256, 0, stream>>>(xA, Wt2, XR, nullptr, Nn, 64, 64, 256);
  agg_kernel<<<aggBlocks, 256, 0, stream>>>(XR, offs, srcs, b2, nullptr, nullptr, xB, 0);
  // --- layer 3 + layernorm ---
  gemm_bf16_kernel<<<gemmBlocks, 256, 0, stream>>>(xB, Wt3, XR, nullptr, Nn, 64, 64, 256);
  agg_kernel<<<aggBlocks, 256, 0, stream>>>(XR, offs, srcs, b3, lng, lnb, xA, 1);

  // --- heads ---
  gemm_bf16_kernel<<<gemmBlocks, 256, 0, stream>>>(xA, Wth, XR, biasH, Nn, 64, 64, 128);
  edge_head_kernel<<<(Ee + 255) / 256, 256, 0, stream>>>(XR, ei, ew2, eb2, out);
  node_head_kernel<<<(Nn + 255) / 256, 256, 0, stream>>>(xA, nw1, nb1, nw2, nb2, out);
}